// Round 9
// baseline (1310.510 us; speedup 1.0000x reference)
//
#include <hip/hip_runtime.h>
#include <math.h>

#define S_LEN   2048
#define HIDDEN  4096
#define N_HEADS 32
#define N_KV    8
#define HEAD_DIM 128
#define NCAND   1844      // S - RECENT
#define HEAVY_K 819
#define MASK_LEN 2049     // S + 1

typedef _Float16 f16;
using f32x4  = __attribute__((ext_vector_type(4))) float;
using f32x16 = __attribute__((ext_vector_type(16))) float;
using f16x8  = __attribute__((ext_vector_type(8))) _Float16;
using f16x4  = __attribute__((ext_vector_type(4))) _Float16;
using f16x2  = __attribute__((ext_vector_type(2))) _Float16;
using uint4v = __attribute__((ext_vector_type(4))) unsigned int;

// exp(s*SCALE) == exp2(s*C2); single fused constant, used identically in all
// three attention passes so L, w, cs stay mutually consistent.
#define C2EXP 0.12751879523486166f   // (1/sqrt(128)) * log2(e)

// ---------------------------------------------------------------------------
// Split-f16 MFMA GEMM (mask-critical path), 128x64 tile (verified rounds 7-8).
// C(f32)[M][ldc] = (Ah+Al)[M][K] * (Bh+Bl)[N][K]^T  via 3-term f16 MFMA.
// ---------------------------------------------------------------------------
__global__ __launch_bounds__(256) void gemm_split(
    const f16* __restrict__ Ah, const f16* __restrict__ Al,
    const f16* __restrict__ Bh, const f16* __restrict__ Bl,
    float* __restrict__ C, int K, int ldc)
{
  __shared__ __align__(16) f16 Ash[128 * 40];
  __shared__ __align__(16) f16 Asl[128 * 40];
  __shared__ __align__(16) f16 Bsh[64 * 40];
  __shared__ __align__(16) f16 Bsl[64 * 40];
  const int t    = threadIdx.x;
  const int lane = t & 63;
  const int wave = t >> 6;
  const int mbase = (wave >> 1) * 64;   // 2 waves along M
  const int nbase = (wave & 1) * 32;    // 2 waves along N
  const int bm = blockIdx.y << 7;
  const int bn = blockIdx.x << 6;
  const int arow = t >> 1;              // 0..127
  const int acol = (t & 1) * 16;        // 0 | 16
  const int brow = t >> 2;              // 0..63
  const int bcol = (t & 3) * 8;         // 0,8,16,24
  const int l16 = lane & 15;
  const int lk  = (lane >> 4) * 8;

  f32x4 acc[4][2];
#pragma unroll
  for (int i = 0; i < 4; i++)
#pragma unroll
    for (int j = 0; j < 2; j++) acc[i][j] = (f32x4){0.f, 0.f, 0.f, 0.f};

  for (int k0 = 0; k0 < K; k0 += 32) {
    const f16* gah = Ah + (size_t)(bm + arow) * K + k0 + acol;
    const f16* gal = Al + (size_t)(bm + arow) * K + k0 + acol;
    const f16* gbh = Bh + (size_t)(bn + brow) * K + k0 + bcol;
    const f16* gbl = Bl + (size_t)(bn + brow) * K + k0 + bcol;
    f16x8 vah0 = *(const f16x8*)(gah);
    f16x8 vah1 = *(const f16x8*)(gah + 8);
    f16x8 val0 = *(const f16x8*)(gal);
    f16x8 val1 = *(const f16x8*)(gal + 8);
    f16x8 vbh = *(const f16x8*)(gbh);
    f16x8 vbl = *(const f16x8*)(gbl);
    __syncthreads();
    *(f16x8*)(Ash + arow * 40 + acol)     = vah0;
    *(f16x8*)(Ash + arow * 40 + acol + 8) = vah1;
    *(f16x8*)(Asl + arow * 40 + acol)     = val0;
    *(f16x8*)(Asl + arow * 40 + acol + 8) = val1;
    *(f16x8*)(Bsh + brow * 40 + bcol) = vbh;
    *(f16x8*)(Bsl + brow * 40 + bcol) = vbl;
    __syncthreads();

    f16x8 afh[4], afl[4], bfh[2], bfl[2];
#pragma unroll
    for (int i = 0; i < 4; i++) {
      afh[i] = *(const f16x8*)(Ash + (mbase + i * 16 + l16) * 40 + lk);
      afl[i] = *(const f16x8*)(Asl + (mbase + i * 16 + l16) * 40 + lk);
    }
#pragma unroll
    for (int j = 0; j < 2; j++) {
      bfh[j] = *(const f16x8*)(Bsh + (nbase + j * 16 + l16) * 40 + lk);
      bfl[j] = *(const f16x8*)(Bsl + (nbase + j * 16 + l16) * 40 + lk);
    }
#pragma unroll
    for (int i = 0; i < 4; i++)
#pragma unroll
      for (int j = 0; j < 2; j++) {
        acc[i][j] = __builtin_amdgcn_mfma_f32_16x16x32_f16(afh[i], bfh[j], acc[i][j], 0, 0, 0);
        acc[i][j] = __builtin_amdgcn_mfma_f32_16x16x32_f16(afh[i], bfl[j], acc[i][j], 0, 0, 0);
        acc[i][j] = __builtin_amdgcn_mfma_f32_16x16x32_f16(afl[i], bfh[j], acc[i][j], 0, 0, 0);
      }
  }

  const int rr = (lane >> 4) * 4;
#pragma unroll
  for (int i = 0; i < 4; i++)
#pragma unroll
    for (int j = 0; j < 2; j++)
#pragma unroll
      for (int r = 0; r < 4; r++)
        C[(size_t)(bm + mbase + i * 16 + rr + r) * ldc + bn + nbase + j * 16 + l16]
            = acc[i][j][r];
}

// ---------------------------------------------------------------------------
// f16 MFMA GEMM, 128x128 tile (tolerance path, Wo).  (verified rounds 4-8)
// ---------------------------------------------------------------------------
__global__ __launch_bounds__(256) void gemm_f16_128(
    const f16* __restrict__ A, const f16* __restrict__ BT,
    float* __restrict__ C, int K, int ldc)
{
  __shared__ __align__(16) f16 As[128 * 40];
  __shared__ __align__(16) f16 Bs[128 * 40];
  const int t    = threadIdx.x;
  const int lane = t & 63;
  const int wave = t >> 6;
  const int mbase = (wave >> 1) * 64;
  const int nbase = (wave & 1) * 64;
  const int bm = blockIdx.y << 7;
  const int bn = blockIdx.x << 7;
  const int srow = t >> 1;
  const int scol = (t & 1) * 16;
  const int l16 = lane & 15;
  const int lk  = (lane >> 4) * 8;

  f32x4 acc[4][4];
#pragma unroll
  for (int i = 0; i < 4; i++)
#pragma unroll
    for (int j = 0; j < 4; j++) acc[i][j] = (f32x4){0.f, 0.f, 0.f, 0.f};

  for (int k0 = 0; k0 < K; k0 += 32) {
    const f16* ga = A  + (size_t)(bm + srow) * K + k0 + scol;
    const f16* gb = BT + (size_t)(bn + srow) * K + k0 + scol;
    f16x8 va0 = *(const f16x8*)(ga);
    f16x8 va1 = *(const f16x8*)(ga + 8);
    f16x8 vb0 = *(const f16x8*)(gb);
    f16x8 vb1 = *(const f16x8*)(gb + 8);
    __syncthreads();
    *(f16x8*)(As + srow * 40 + scol)     = va0;
    *(f16x8*)(As + srow * 40 + scol + 8) = va1;
    *(f16x8*)(Bs + srow * 40 + scol)     = vb0;
    *(f16x8*)(Bs + srow * 40 + scol + 8) = vb1;
    __syncthreads();

    f16x8 af[4], bf[4];
#pragma unroll
    for (int i = 0; i < 4; i++) {
      af[i] = *(const f16x8*)(As + (mbase + i * 16 + l16) * 40 + lk);
      bf[i] = *(const f16x8*)(Bs + (nbase + i * 16 + l16) * 40 + lk);
    }
#pragma unroll
    for (int i = 0; i < 4; i++)
#pragma unroll
      for (int j = 0; j < 4; j++)
        acc[i][j] = __builtin_amdgcn_mfma_f32_16x16x32_f16(af[i], bf[j], acc[i][j], 0, 0, 0);
  }

  const int rr = (lane >> 4) * 4;
#pragma unroll
  for (int i = 0; i < 4; i++)
#pragma unroll
    for (int j = 0; j < 4; j++)
#pragma unroll
      for (int r = 0; r < 4; r++)
        C[(size_t)(bm + mbase + i * 16 + rr + r) * ldc + bn + nbase + j * 16 + l16]
            = acc[i][j][r];
}

// ---------------------------------------------------------------------------
// f16 MFMA GEMM 64x64 (V projection: N=1024 wants block count).
// ---------------------------------------------------------------------------
__global__ __launch_bounds__(256) void gemm_f16(
    const f16* __restrict__ A, const f16* __restrict__ BT,
    float* __restrict__ C, int M, int N, int K)
{
  __shared__ __align__(16) f16 As[64 * 40];
  __shared__ __align__(16) f16 Bs[64 * 40];
  const int t    = threadIdx.x;
  const int lane = t & 63;
  const int wave = t >> 6;
  const int mbase = (wave >> 1) * 32;
  const int nbase = (wave & 1) * 32;
  const int bm = blockIdx.y << 6;
  const int bn = blockIdx.x << 6;
  const int srow = t >> 2;
  const int scol = (t & 3) * 8;
  const int l16 = lane & 15;
  const int lk  = (lane >> 4) * 8;

  f32x4 acc00 = {0.f,0.f,0.f,0.f}, acc01 = {0.f,0.f,0.f,0.f};
  f32x4 acc10 = {0.f,0.f,0.f,0.f}, acc11 = {0.f,0.f,0.f,0.f};

  for (int k0 = 0; k0 < K; k0 += 32) {
    f16x8 av = *(const f16x8*)(A  + (size_t)(bm + srow) * K + k0 + scol);
    f16x8 bv = *(const f16x8*)(BT + (size_t)(bn + srow) * K + k0 + scol);
    __syncthreads();
    *(f16x8*)(As + srow * 40 + scol) = av;
    *(f16x8*)(Bs + srow * 40 + scol) = bv;
    __syncthreads();
    f16x8 a0 = *(const f16x8*)(As + (mbase + l16)      * 40 + lk);
    f16x8 a1 = *(const f16x8*)(As + (mbase + 16 + l16) * 40 + lk);
    f16x8 b0 = *(const f16x8*)(Bs + (nbase + l16)      * 40 + lk);
    f16x8 b1 = *(const f16x8*)(Bs + (nbase + 16 + l16) * 40 + lk);
    acc00 = __builtin_amdgcn_mfma_f32_16x16x32_f16(a0, b0, acc00, 0, 0, 0);
    acc01 = __builtin_amdgcn_mfma_f32_16x16x32_f16(a0, b1, acc01, 0, 0, 0);
    acc10 = __builtin_amdgcn_mfma_f32_16x16x32_f16(a1, b0, acc10, 0, 0, 0);
    acc11 = __builtin_amdgcn_mfma_f32_16x16x32_f16(a1, b1, acc11, 0, 0, 0);
  }

  const int rr = (lane >> 4) * 4;
#pragma unroll
  for (int r = 0; r < 4; r++) {
    C[(size_t)(bm + mbase +      rr + r) * N + bn + nbase +      l16] = acc00[r];
    C[(size_t)(bm + mbase +      rr + r) * N + bn + nbase + 16 + l16] = acc01[r];
    C[(size_t)(bm + mbase + 16 + rr + r) * N + bn + nbase +      l16] = acc10[r];
    C[(size_t)(bm + mbase + 16 + rr + r) * N + bn + nbase + 16 + l16] = acc11[r];
  }
}

// ---------------------------------------------------------------------------
// f32 [K][N] -> f16 [N][K] transpose-convert.
// ---------------------------------------------------------------------------
__global__ __launch_bounds__(256) void conv_T_f16(
    const float* __restrict__ src, f16* __restrict__ dst, int K, int N)
{
  __shared__ float tile[32][33];
  const int tj = blockIdx.x;
  const int ti = blockIdx.y;
  const int t = threadIdx.x;
  for (int idx = t; idx < 1024; idx += 256) {
    int r = idx >> 5, c = idx & 31;
    tile[r][c] = src[(size_t)(ti * 32 + r) * N + tj * 32 + c];
  }
  __syncthreads();
  for (int idx = t; idx < 1024; idx += 256) {
    int r = idx >> 5, c = idx & 31;
    dst[(size_t)(tj * 32 + r) * K + ti * 32 + c] = (f16)tile[c][r];
  }
}

// ---------------------------------------------------------------------------
// f32 [K][N] cols [n0,n0+32*gridDim.x) -> split f16 hi/lo [NC][K] transpose.
// ---------------------------------------------------------------------------
__global__ __launch_bounds__(256) void conv_T_split(
    const float* __restrict__ src, f16* __restrict__ hi, f16* __restrict__ lo,
    int K, int N, int n0)
{
  __shared__ float tile[32][33];
  const int tj = blockIdx.x;
  const int ti = blockIdx.y;
  const int t = threadIdx.x;
  for (int idx = t; idx < 1024; idx += 256) {
    int r = idx >> 5, c = idx & 31;
    tile[r][c] = src[(size_t)(ti * 32 + r) * N + n0 + tj * 32 + c];
  }
  __syncthreads();
  for (int idx = t; idx < 1024; idx += 256) {
    int r = idx >> 5, c = idx & 31;
    float x = tile[c][r];
    f16 h = (f16)x;
    hi[(size_t)(tj * 32 + r) * K + ti * 32 + c] = h;
    lo[(size_t)(tj * 32 + r) * K + ti * 32 + c] = (f16)(x - (float)h);
  }
}

// ---------------------------------------------------------------------------
// f32 -> (f16 hi, f16 lo) split, row-major.  hi = rne(x); lo = rne(x - hi).
// ---------------------------------------------------------------------------
__global__ __launch_bounds__(256) void split_f16(
    const float* __restrict__ src, f16* __restrict__ hi, f16* __restrict__ lo,
    int n4)
{
  int i = blockIdx.x * 256 + threadIdx.x;
  if (i >= n4) return;
  float4 v = ((const float4*)src)[i];
  float vv[4] = {v.x, v.y, v.z, v.w};
  f16x4 h, l;
#pragma unroll
  for (int j = 0; j < 4; j++) {
    f16 hh = (f16)vv[j];
    h[j] = hh;
    l[j] = (f16)(vv[j] - (float)hh);
  }
  ((f16x4*)hi)[i] = h;
  ((f16x4*)lo)[i] = l;
}

// ---------------------------------------------------------------------------
// Attention pass 1: softmax denominators L[q].  Round-9 change: the 24-MFMA
// SERIAL accumulator chain is split into 3 INDEPENDENT chains (hh, hl, lh),
// summed once at the end -- 3-way MFMA ILP, chain depth 24 -> 8.  Score
// differs only by f32 reorder noise (< the split residual already absorbed).
// kvh-pinned 1-D grid + balanced q-tile pairing (verified round 8).
// ---------------------------------------------------------------------------
__global__ __launch_bounds__(256) void attn_l(
    const f16* __restrict__ Qh, const f16* __restrict__ Ql,
    const f16* __restrict__ Kh, const f16* __restrict__ Kl,
    float* __restrict__ Lrow)
{
  __shared__ __align__(16) f16 Khs[32 * 136];
  __shared__ __align__(16) f16 Kls[32 * 136];
  const int t    = threadIdx.x;
  const int lane = t & 63;
  const int wave = t >> 6;
  const int l31  = lane & 31;
  const int gp   = lane >> 5;
  const int bid  = (int)blockIdx.x;            // 512 blocks
  const int kvh  = bid & 7;
  const int h    = kvh * 4 + ((bid >> 3) & 3);
  const int hi5  = bid >> 5;                   // 0..15
  const int qt   = hi5 < 8 ? 15 - hi5 : hi5 - 8;   // balanced pairing
  const int q0   = qt << 7;
  const int qw   = q0 + wave * 32;
  const int qg   = qw + l31;

  f16x8 qhf[8], qlf[8];
  {
    const f16* qp  = Qh + (size_t)qg * HIDDEN + h * HEAD_DIM + 8 * gp;
    const f16* qp2 = Ql + (size_t)qg * HIDDEN + h * HEAD_DIM + 8 * gp;
#pragma unroll
    for (int c = 0; c < 8; c++) {
      qhf[c] = *(const f16x8*)(qp  + c * 16);
      qlf[c] = *(const f16x8*)(qp2 + c * 16);
    }
  }

  float Lacc = 0.f;
  const int ntiles = (q0 >> 5) + 4;
  for (int kt = 0; kt < ntiles; kt++) {
    const int k0 = kt << 5;
    __syncthreads();
    for (int i = t; i < 512; i += 256) {
      int r = i >> 4, c = i & 15;
      size_t g = (size_t)(k0 + r) * (N_KV * HEAD_DIM) + kvh * HEAD_DIM + c * 8;
      *(f16x8*)(Khs + r * 136 + c * 8) = *(const f16x8*)(Kh + g);
      *(f16x8*)(Kls + r * 136 + c * 8) = *(const f16x8*)(Kl + g);
    }
    __syncthreads();
    if (k0 > qw + 31) continue;   // after both barriers: barrier counts uniform

    f32x16 a_hh, a_hl, a_lh;
#pragma unroll
    for (int i = 0; i < 16; i++) { a_hh[i] = 0.f; a_hl[i] = 0.f; a_lh[i] = 0.f; }
#pragma unroll
    for (int c = 0; c < 8; c++) {
      f16x8 ah = *(const f16x8*)(Khs + l31 * 136 + c * 16 + 8 * gp);
      f16x8 al = *(const f16x8*)(Kls + l31 * 136 + c * 16 + 8 * gp);
      a_hh = __builtin_amdgcn_mfma_f32_32x32x16_f16(ah, qhf[c], a_hh, 0, 0, 0);
      a_hl = __builtin_amdgcn_mfma_f32_32x32x16_f16(ah, qlf[c], a_hl, 0, 0, 0);
      a_lh = __builtin_amdgcn_mfma_f32_32x32x16_f16(al, qhf[c], a_lh, 0, 0, 0);
    }
    float ws = 0.f;
#pragma unroll
    for (int r = 0; r < 16; r++) {
      int kg = k0 + (r & 3) + 8 * (r >> 2) + 4 * gp;
      float sv = (a_hh[r] + a_hl[r]) + a_lh[r];
      float e = exp2f(sv * C2EXP);
      ws += (kg <= qg) ? e : 0.f;
    }
    Lacc += ws;
  }

  float tot = Lacc + __shfl_xor(Lacc, 32);
  if (lane < 32) Lrow[h * S_LEN + qw + lane] = tot;
}

// ---------------------------------------------------------------------------
// Attention pass 2: O = softmax(QK^T) V via MFMA.  Balanced pairing + Vt
// prefetch (verified round 8).  Unchanged this round.
// ---------------------------------------------------------------------------
__global__ __launch_bounds__(256) void attn_o(
    const f16* __restrict__ Qh, const f16* __restrict__ Kh,
    const f16* __restrict__ Vt, const float* __restrict__ Lrow,
    f16* __restrict__ attnb)
{
  __shared__ __align__(16) f16 Khs[32 * 136];
  const int t    = threadIdx.x;
  const int lane = t & 63;
  const int wave = t >> 6;
  const int l31  = lane & 31;
  const int gp   = lane >> 5;
  const int bid  = (int)blockIdx.x;            // 512 blocks
  const int kvh  = bid & 7;
  const int h    = kvh * 4 + ((bid >> 3) & 3);
  const int hi5  = bid >> 5;                   // 0..15
  const int qt   = hi5 < 8 ? 15 - hi5 : hi5 - 8;   // balanced pairing
  const int q0   = qt << 7;
  const int qw   = q0 + wave * 32;
  const int qg   = qw + l31;

  f16x8 qhf[8];
  {
    const f16* qp = Qh + (size_t)qg * HIDDEN + h * HEAD_DIM + 8 * gp;
#pragma unroll
    for (int c = 0; c < 8; c++) qhf[c] = *(const f16x8*)(qp + c * 16);
  }
  const float iL = 1.0f / Lrow[h * S_LEN + qg];

  f32x16 oacc[4];
#pragma unroll
  for (int m = 0; m < 4; m++)
#pragma unroll
    for (int i = 0; i < 16; i++) oacc[m][i] = 0.f;

  const int ntiles = (q0 >> 5) + 4;
  for (int kt = 0; kt < ntiles; kt++) {
    const int k0 = kt << 5;
    __syncthreads();
    for (int i = t; i < 512; i += 256) {
      int r = i >> 4, c = i & 15;
      size_t g = (size_t)(k0 + r) * (N_KV * HEAD_DIM) + kvh * HEAD_DIM + c * 8;
      *(f16x8*)(Khs + r * 136 + c * 8) = *(const f16x8*)(Kh + g);
    }
    __syncthreads();
    if (k0 > qw + 31) continue;

    // --- Vt prefetch: independent of QK/exp/pack, issue FIRST (hides L2) ---
    f16x8 vr0[4], vr1[4];
#pragma unroll
    for (int mt = 0; mt < 4; mt++) {
      const f16* vp = Vt + (size_t)(kvh * HEAD_DIM + mt * 32 + l31) * S_LEN
                         + k0 + 8 * gp;
      vr0[mt] = *(const f16x8*)(vp);
      vr1[mt] = *(const f16x8*)(vp + 16);
    }

    f32x16 acc;
#pragma unroll
    for (int i = 0; i < 16; i++) acc[i] = 0.f;
#pragma unroll
    for (int c = 0; c < 8; c++) {
      f16x8 ah = *(const f16x8*)(Khs + l31 * 136 + c * 16 + 8 * gp);
      acc = __builtin_amdgcn_mfma_f32_32x32x16_f16(ah, qhf[c], acc, 0, 0, 0);
    }

    float wv[16];
#pragma unroll
    for (int r = 0; r < 16; r++) {
      int kg = k0 + (r & 3) + 8 * (r >> 2) + 4 * gp;
      wv[r] = (kg <= qg) ? exp2f(acc[r] * C2EXP) * iL : 0.f;
    }

    unsigned p[8], x[8];
#pragma unroll
    for (int j = 0; j < 8; j++)
      p[j] = __builtin_bit_cast(unsigned,
               __builtin_amdgcn_cvt_pkrtz(wv[2 * j], wv[2 * j + 1]));
#pragma unroll
    for (int j = 0; j < 8; j++)
      x[j] = (unsigned)__shfl_xor((int)p[j], 32);

    uint4v cc0, cc1;   // B-frag: row(q)=lane&31, k = gp*8 + j
    cc0[0] = gp ? x[2] : p[0]; cc0[1] = gp ? x[3] : p[1];
    cc0[2] = gp ? p[2] : x[0]; cc0[3] = gp ? p[3] : x[1];
    cc1[0] = gp ? x[6] : p[4]; cc1[1] = gp ? x[7] : p[5];
    cc1[2] = gp ? p[6] : x[4]; cc1[3] = gp ? p[7] : x[5];
    f16x8 pf0 = __builtin_bit_cast(f16x8, cc0);   // keys k0+0..15
    f16x8 pf1 = __builtin_bit_cast(f16x8, cc1);   // keys k0+16..31

#pragma unroll
    for (int mt = 0; mt < 4; mt++) {
      oacc[mt] = __builtin_amdgcn_mfma_f32_32x32x16_f16(vr0[mt], pf0, oacc[mt], 0, 0, 0);
      oacc[mt] = __builtin_amdgcn_mfma_f32_32x32x16_f16(vr1[mt], pf1, oacc[mt], 0, 0, 0);
    }
  }

  f16* ob = attnb + (size_t)qg * HIDDEN + h * HEAD_DIM;
#pragma unroll
  for (int mt = 0; mt < 4; mt++)
#pragma unroll
    for (int rq = 0; rq < 4; rq++) {
      int d = mt * 32 + 8 * rq + 4 * gp;
      f16x4 o;
      o[0] = (f16)oacc[mt][rq * 4 + 0];
      o[1] = (f16)oacc[mt][rq * 4 + 1];
      o[2] = (f16)oacc[mt][rq * 4 + 2];
      o[3] = (f16)oacc[mt][rq * 4 + 3];
      *(f16x4*)(ob + d) = o;
    }
}

// ---------------------------------------------------------------------------
// Attention pass 3: cs[h][key] = sum_q w[q,key]  (mask-critical, split-exact).
// Round-9: 24-MFMA serial chain -> 3 independent chains (hh/hl/lh), summed
// at the end.  Rest (1856 blocks, mod-4 wave split, XCD pin) verified r6-8.
// ---------------------------------------------------------------------------
__global__ __launch_bounds__(256) void attn_cs(
    const f16* __restrict__ Qh, const f16* __restrict__ Ql,
    const f16* __restrict__ Kh, const f16* __restrict__ Kl,
    const float* __restrict__ Lrow, float* __restrict__ cs)
{
  const int t    = threadIdx.x;
  const int lane = t & 63;
  const int wave = t >> 6;
  const int l31  = lane & 31;
  const int gp   = lane >> 5;
  const int bid  = (int)blockIdx.x;        // 58*32 = 1856 blocks
  const int h    = bid & 31;               // bid%8 = h%8 -> XCD pin per head
  const int kvh  = h >> 2;
  const int kb   = (bid >> 5) << 5;        // this block's 32-key strip

  f16x8 kah[8], kal[8];
  {
    const f16* kp  = Kh + (size_t)(kb + l31) * (N_KV * HEAD_DIM) + kvh * HEAD_DIM + 8 * gp;
    const f16* kp2 = Kl + (size_t)(kb + l31) * (N_KV * HEAD_DIM) + kvh * HEAD_DIM + 8 * gp;
#pragma unroll
    for (int c = 0; c < 8; c++) {
      kah[c] = *(const f16x8*)(kp  + c * 16);
      kal[c] = *(const f16x8*)(kp2 + c * 16);
    }
  }

  float csa[16];
#pragma unroll
  for (int r = 0; r < 16; r++) csa[r] = 0.f;

  for (int q0 = kb + wave * 32; q0 < S_LEN; q0 += 128) {
    const int qg = q0 + l31;
    const float iL = 1.0f / Lrow[h * S_LEN + qg];
    const f16* qp  = Qh + (size_t)qg * HIDDEN + h * HEAD_DIM + 8 * gp;
    const f16* qp2 = Ql + (size_t)qg * HIDDEN + h * HEAD_DIM + 8 * gp;

    f32x16 a_hh, a_hl, a_lh;
#pragma unroll
    for (int i = 0; i < 16; i++) { a_hh[i] = 0.f; a_hl[i] = 0.f; a_lh[i] = 0.f; }
#pragma unroll
    for (int c = 0; c < 8; c++) {
      f16x8 bh = *(const f16x8*)(qp  + c * 16);
      f16x8 bl = *(const f16x8*)(qp2 + c * 16);
      a_hh = __builtin_amdgcn_mfma_f32_32x32x16_f16(kah[c], bh, a_hh, 0, 0, 0);
      a_hl = __builtin_amdgcn_mfma_f32_32x32x16_f16(kah[c], bl, a_hl, 0, 0, 0);
      a_lh = __builtin_amdgcn_mfma_f32_32x32x16_f16(kal[c], bh, a_lh, 0, 0, 0);
    }
#pragma unroll
    for (int r = 0; r < 16; r++) {
      int kg = kb + (r & 3) + 8 * (r >> 2) + 4 * gp;
      float sv = (a_hh[r] + a_hl[r]) + a_lh[r];
      csa[r] += (kg <= qg) ? exp2f(sv * C2EXP) * iL : 0.f;
    }
  }

#pragma unroll
  for (int st = 1; st < 32; st <<= 1)
#pragma unroll
    for (int r = 0; r < 16; r++) csa[r] += __shfl_xor(csa[r], st);

  if (l31 == 0) {
#pragma unroll
    for (int r = 0; r < 16; r++)
      atomicAdd(&cs[h * S_LEN + kb + (r & 3) + 8 * (r >> 2) + 4 * gp], csa[r]);
  }
}

// ---------------------------------------------------------------------------
// Exact top-HEAVY_K via O(n^2) ranking -- one candidate per thread, 9 x 32
// blocks.  Identical comparison + tie-break (jj < i) -> mask bit-identical.
// (verified rounds 4-8)
// ---------------------------------------------------------------------------
__global__ __launch_bounds__(256) void topk_mask_kernel(
    const float* __restrict__ cs, float* __restrict__ maskout)
{
  const int h = blockIdx.y;
  __shared__ float sv[NCAND];
  const float* s = cs + h * S_LEN;
  const int t = threadIdx.x;
  for (int i = t; i < NCAND; i += 256) sv[i] = s[i];
  __syncthreads();

  const int i = blockIdx.x * 256 + t;
  if (i >= MASK_LEN) return;
  float val = (i >= NCAND + 1) ? 1.0f : 0.0f;
  if (i < NCAND) {
    const float v = sv[i];
    int cnt = 0;
#pragma unroll 4
    for (int jj = 0; jj < NCAND; jj++) {
      float x = sv[jj];
      cnt += ((x > v) || (x == v && jj < i)) ? 1 : 0;
    }
    val = (cnt < HEAVY_K) ? 1.0f : 0.0f;
  }
  maskout[h * MASK_LEN + i] = val;
}

__global__ __launch_bounds__(256) void zero_kernel(float* __restrict__ p, int n)
{
  int i = blockIdx.x * 256 + threadIdx.x;
  if (i < n) p[i] = 0.f;
}

// ---------------------------------------------------------------------------
// In-place RoPE.
// ---------------------------------------------------------------------------
__global__ __launch_bounds__(256) void rope_kernel(
    float* __restrict__ buf, const int* __restrict__ pos_ids, int ncols)
{
  __shared__ float invf_s[64];
  if (threadIdx.x < 64)
    invf_s[threadIdx.x] =
        (float)(1.0 / pow(10000.0, (double)threadIdx.x * (1.0 / 64.0)));
  __syncthreads();

  int i = blockIdx.x * 256 + threadIdx.x;
  int half = ncols >> 1;
  int total = S_LEN * half;
  if (i >= total) return;
  int row = i / half;
  int rem = i - row * half;
  int hh = rem >> 6;
  int d  = rem & 63;
  float p = (float)pos_ids[row];
  float ang = p * invf_s[d];
  float c = cosf(ang);
  float s = sinf(ang);
  float* base = buf + (size_t)row * ncols + hh * HEAD_DIM;
  float x0 = base[d];
  float x1 = base[d + 64];
  base[d]      = x0 * c - x1 * s;
  base[d + 64] = x1 * c + x0 * s;
}

// ---------------------------------------------------------------------------
// Workspace layout (109,576,192 B total -- unchanged from round 2).
// ---------------------------------------------------------------------------
extern "C" void kernel_launch(void* const* d_in, const int* in_sizes, int n_in,
                              void* d_out, int out_size, void* d_ws, size_t ws_size,
                              hipStream_t stream)
{
  (void)in_sizes; (void)n_in; (void)out_size; (void)ws_size;
  const float* hs = (const float*)d_in[0];
  const int*  pos = (const int*)d_in[1];
  const float* Wq = (const float*)d_in[2];
  const float* Wk = (const float*)d_in[3];
  const float* Wv = (const float*)d_in[4];
  const float* Wo = (const float*)d_in[5];
  float* out = (float*)d_out;

  char* w = (char*)d_ws;
  float* Qraw  = (float*)(w);                          // 32 MiB
  f16*   WoT   = (f16*)  (w);                          // overlays Qraw
  f16*   WqTl  = (f16*)  (w + 33554432);               // 16 MiB (32..48)
  float* Kraw  = (float*)(w + 33554432);               // 8 MiB, after Wq gemms
  f16*   Vt    = (f16*)  (w + 33554432);               // 4 MiB, after K split
  float* Vraw  = (float*)(w + 41943040);               // 8 MiB
  float* Lrow  = (float*)(w + 50331648);
  float* cs    = (float*)(w + 50593792);
  f16*   hsh   = (f16*)  (w + 50855936);               // 16 MiB (48.5..64.5)
  f16*   attnb = (f16*)  (w + 50855936);               // overlays hsh
  f16*   hsl   = (f16*)  (w + 67633152);               // 16 MiB (64.5..80.5)
  f16*   Qh    = (f16*)  (w + 67633152);               // overlays hsl
  f16*   WqTh  = (f16*)  (w + 84410368);               // 16 MiB (80.5..96.5)
  f16*   WkTh  = (f16*)  (w + 84410368);               //  8 MiB
  f16*   WvT   = (f16*)  (w + 84410368);               //  8 MiB
  f16*   Ql    = (f16*)  (w + 84410368);               // overlays, after V gemm
  f16*   WkTl  = (f16*)  (w + 92798976);               //  8 MiB (88.5..96.5)
  f16*   Kh    = (f16*)  (w + 101187584);              //  4 MiB
  f16*   Kl    = (f16*)  (w + 105381888);              //  4 MiB -> end 104.5 MiB

  dim3 blk(256);

  // --- split hidden_states once (A-operand for Q, K, V gemms) ---
  split_f16<<<(S_LEN * HIDDEN / 4 + 255) / 256, blk, 0, stream>>>(
      hs, hsh, hsl, S_LEN * HIDDEN / 4);

  // --- Q = hs @ Wq, split-exact, two N=2048 chunks (128x64 tiles: 512 blk) ---
  conv_T_split<<<dim3(2048 / 32, HIDDEN / 32), blk, 0, stream>>>(
      Wq, WqTh, WqTl, HIDDEN, HIDDEN, 0);
  gemm_split<<<dim3(2048 / 64, S_LEN / 128), blk, 0, stream>>>(
      hsh, hsl, WqTh, WqTl, Qraw, HIDDEN, HIDDEN);
  conv_T_split<<<dim3(2048 / 32, HIDDEN / 32), blk, 0, stream>>>(
      Wq, WqTh, WqTl, HIDDEN, HIDDEN, 2048);
  gemm_split<<<dim3(2048 / 64, S_LEN / 128), blk, 0, stream>>>(
      hsh, hsl, WqTh, WqTl, Qraw + 2048, HIDDEN, HIDDEN);

  // --- K = hs @ Wk, split-exact (128x64 tiles: 256 blocks) ---
  conv_T_split<<<dim3((N_KV * HEAD_DIM) / 32, HIDDEN / 32), blk, 0, stream>>>(
      Wk, WkTh, WkTl, HIDDEN, N_KV * HEAD_DIM, 0);
  gemm_split<<<dim3((N_KV * HEAD_DIM) / 64, S_LEN / 128), blk, 0, stream>>>(
      hsh, hsl, WkTh, WkTl, Kraw, HIDDEN, N_KV * HEAD_DIM);

  // --- V = hs @ Wv, f16 (tolerance path) ---
  conv_T_f16<<<dim3((N_KV * HEAD_DIM) / 32, HIDDEN / 32), blk, 0, stream>>>(
      Wv, WvT, HIDDEN, N_KV * HEAD_DIM);
  gemm_f16<<<dim3((N_KV * HEAD_DIM) / 64, S_LEN / 64), blk, 0, stream>>>(
      hsh, WvT, Vraw, S_LEN, N_KV * HEAD_DIM, HIDDEN);

  // --- RoPE (f32, in place) ---
  rope_kernel<<<(S_LEN * (HIDDEN / 2) + 255) / 256, blk, 0, stream>>>(
      Qraw, pos, HIDDEN);
  rope_kernel<<<(S_LEN * (N_KV * HEAD_DIM / 2) + 255) / 256, blk, 0, stream>>>(
      Kraw, pos, N_KV * HEAD_DIM);

  // --- splits for attention ---
  split_f16<<<(S_LEN * HIDDEN / 4 + 255) / 256, blk, 0, stream>>>(
      Qraw, Qh, Ql, S_LEN * HIDDEN / 4);
  split_f16<<<(S_LEN * N_KV * HEAD_DIM / 4 + 255) / 256, blk, 0, stream>>>(
      Kraw, Kh, Kl, S_LEN * N_KV * HEAD_DIM / 4);
  conv_T_f16<<<dim3((N_KV * HEAD_DIM) / 32, S_LEN / 32), blk, 0, stream>>>(
      Vraw, Vt, S_LEN, N_KV * HEAD_DIM);
  conv_T_f16<<<dim3(HIDDEN / 32, HIDDEN / 32), blk, 0, stream>>>(
      Wo, WoT, HIDDEN, HIDDEN);   // Qraw dead (split done) -> safe overlay

  // --- attention (1-D XCD-pinned grids, balanced pairing) ---
  attn_l<<<dim3((S_LEN / 128) * N_HEADS), blk, 0, stream>>>(
      Qh, Ql, Kh, Kl, Lrow);
  attn_o<<<dim3((S_LEN / 128) * N_HEADS), blk, 0, stream>>>(
      Qh, Kh, Vt, Lrow, attnb);
  zero_kernel<<<(N_HEADS * S_LEN + 255) / 256, blk, 0, stream>>>(
      cs, N_HEADS * S_LEN);
  attn_cs<<<dim3(((NCAND + 31) / 32) * N_HEADS), blk, 0, stream>>>(
      Qh, Ql, Kh, Kl, Lrow, cs);
  topk_mask_kernel<<<dim3((MASK_LEN + 255) / 256, N_HEADS), blk, 0, stream>>>(
      cs, out + (size_t)S_LEN * HIDDEN);

  // --- output projection (128x128 tile) ---
  gemm_f16_128<<<dim3(HIDDEN / 128, S_LEN / 128), blk, 0, stream>>>(
      attnb, WoT, out, HIDDEN, HIDDEN);
}